// Round 2
// baseline (1709.266 us; speedup 1.0000x reference)
//
#include <hip/hip_runtime.h>
#include <cstddef>

#define B_   4
#define S_   8192
#define D_   512
#define H_   8
#define HD_  64
#define NROW (B_ * S_)          // 32768
#define QKV_LD 1536             // row stride of qkv workspace

__device__ __forceinline__ float phi_f(float x) {
    // elu(x)+1 : x>0 -> x+1 ; else exp(x)
    return x > 0.0f ? x + 1.0f : expf(x);
}

// ---------------------------------------------------------------------------
// Mask layout detector: writes 1 to *flag if mask buffer is byte-per-element
// (bool), 0 if 4-byte-per-element (int32/float32). Single block.
// ---------------------------------------------------------------------------
__global__ void detect_mask(const unsigned char* __restrict__ m, int* __restrict__ flag) {
    __shared__ int sany;
    if (threadIdx.x == 0) sany = 0;
    __syncthreads();
    int any = 0;
    // scan byte offsets == 1 (mod 4) within first NROW bytes
    for (int i = 1 + 4 * (int)threadIdx.x; i < NROW; i += 4 * 256) any |= m[i];
    if (any) atomicOr(&sany, 1);
    __syncthreads();
    if (threadIdx.x == 0) *flag = sany ? 1 : 0;
}

// ---------------------------------------------------------------------------
// NT GEMM: C[m][n] = sum_k A[m][k] * Bm[n][k] + bias[n], with optional
// qkv epilogue (mode 0): n<512 -> phi ; 512<=n<1024 -> phi*mask ; else *mask.
// 64x64 tile, BK=16, 256 threads, 4x4 per thread. M,N %64==0, K %16==0.
// ---------------------------------------------------------------------------
__global__ __launch_bounds__(256) void gemm_nt(
    const float* __restrict__ A, int lda,
    const float* __restrict__ Bm, int ldb,
    const float* __restrict__ bias,
    float* __restrict__ C, int ldc,
    int K, int mode,
    const unsigned char* __restrict__ kpm8,
    const int* __restrict__ maskflag)
{
    __shared__ __align__(16) float As[16][68];  // [k][m], 272B rows (16B-aligned)
    __shared__ __align__(16) float Bs[16][68];  // [k][n]

    const int t  = threadIdx.x;
    const int tx = t & 15, ty = t >> 4;
    const int m0 = blockIdx.y * 64, n0 = blockIdx.x * 64;
    const int lr = t >> 2;          // staging row 0..63
    const int lk = (t & 3) * 4;     // staging k offset 0,4,8,12

    float acc[4][4] = {};

    for (int k0 = 0; k0 < K; k0 += 16) {
        const float4 av = *(const float4*)&A[(size_t)(m0 + lr) * lda + k0 + lk];
        const float4 bv = *(const float4*)&Bm[(size_t)(n0 + lr) * ldb + k0 + lk];
        As[lk + 0][lr] = av.x; As[lk + 1][lr] = av.y; As[lk + 2][lr] = av.z; As[lk + 3][lr] = av.w;
        Bs[lk + 0][lr] = bv.x; Bs[lk + 1][lr] = bv.y; Bs[lk + 2][lr] = bv.z; Bs[lk + 3][lr] = bv.w;
        __syncthreads();
        #pragma unroll
        for (int kk = 0; kk < 16; ++kk) {
            const float4 a = *(const float4*)&As[kk][ty * 4];
            const float4 b = *(const float4*)&Bs[kk][tx * 4];
            acc[0][0] += a.x * b.x; acc[0][1] += a.x * b.y; acc[0][2] += a.x * b.z; acc[0][3] += a.x * b.w;
            acc[1][0] += a.y * b.x; acc[1][1] += a.y * b.y; acc[1][2] += a.y * b.z; acc[1][3] += a.y * b.w;
            acc[2][0] += a.z * b.x; acc[2][1] += a.z * b.y; acc[2][2] += a.z * b.z; acc[2][3] += a.z * b.w;
            acc[3][0] += a.w * b.x; acc[3][1] += a.w * b.y; acc[3][2] += a.w * b.z; acc[3][3] += a.w * b.w;
        }
        __syncthreads();
    }

    int mflag = 0;
    if (mode == 0) mflag = *maskflag;

    #pragma unroll
    for (int i = 0; i < 4; ++i) {
        const int r = m0 + ty * 4 + i;
        float mval = 1.0f;
        if (mode == 0) {
            const bool ignore = mflag ? (kpm8[r] != 0)
                                      : (((const int*)kpm8)[r] != 0);
            mval = ignore ? 0.0f : 1.0f;
        }
        float4 o;
        float* op = &o.x;
        #pragma unroll
        for (int j = 0; j < 4; ++j) {
            const int n = n0 + tx * 4 + j;
            float v = acc[i][j] + bias[n];
            if (mode == 0) {
                if (n < D_)            v = phi_f(v);
                else if (n < 2 * D_)   v = phi_f(v) * mval;
                else                   v = v * mval;
            }
            op[j] = v;
        }
        *(float4*)&C[(size_t)r * ldc + n0 + tx * 4] = o;
    }
}

// ---------------------------------------------------------------------------
// Per (head, S-chunk) partial kv = k^T v (64x64) and k_sum (64).
// grid (32, 16), 256 threads. k,v already phi'd/masked in qkv workspace.
// ---------------------------------------------------------------------------
__global__ __launch_bounds__(256) void kv_reduce(
    const float* __restrict__ qkv,
    float* __restrict__ part_kv,   // [32*16][4096]
    float* __restrict__ part_ks)   // [32*16][64]
{
    const int bh = blockIdx.x;      // 0..31
    const int chunk = blockIdx.y;   // 0..15
    const int b = bh >> 3, h = bh & 7;

    __shared__ __align__(16) float Ks[16][64];
    __shared__ __align__(16) float Vs[16][64];

    const int t  = threadIdx.x;
    const int tx = t & 15, ty = t >> 4;
    const int ls = t >> 4;          // staging row 0..15
    const int lc = (t & 15) * 4;    // staging col

    const size_t rowbase = (size_t)b * S_ * QKV_LD;
    const float* kb = qkv + rowbase + D_ + h * HD_;
    const float* vb = qkv + rowbase + 2 * D_ + h * HD_;

    float acc[4][4] = {};
    float ks[4] = {};
    const int s0 = chunk * (S_ / 16);   // 512 rows per chunk

    for (int it = 0; it < S_ / 16; it += 16) {
        const size_t s = (size_t)(s0 + it + ls);
        *(float4*)&Ks[ls][lc] = *(const float4*)&kb[s * QKV_LD + lc];
        *(float4*)&Vs[ls][lc] = *(const float4*)&vb[s * QKV_LD + lc];
        __syncthreads();
        #pragma unroll
        for (int ss = 0; ss < 16; ++ss) {
            const float4 a = *(const float4*)&Ks[ss][ty * 4];
            const float4 v = *(const float4*)&Vs[ss][tx * 4];
            acc[0][0] += a.x * v.x; acc[0][1] += a.x * v.y; acc[0][2] += a.x * v.z; acc[0][3] += a.x * v.w;
            acc[1][0] += a.y * v.x; acc[1][1] += a.y * v.y; acc[1][2] += a.y * v.z; acc[1][3] += a.y * v.w;
            acc[2][0] += a.z * v.x; acc[2][1] += a.z * v.y; acc[2][2] += a.z * v.z; acc[2][3] += a.z * v.w;
            acc[3][0] += a.w * v.x; acc[3][1] += a.w * v.y; acc[3][2] += a.w * v.z; acc[3][3] += a.w * v.w;
            if (tx == 0) { ks[0] += a.x; ks[1] += a.y; ks[2] += a.z; ks[3] += a.w; }
        }
        __syncthreads();
    }

    float* pk = part_kv + (size_t)(bh * 16 + chunk) * 4096;
    #pragma unroll
    for (int i = 0; i < 4; ++i) {
        float4 o; o.x = acc[i][0]; o.y = acc[i][1]; o.z = acc[i][2]; o.w = acc[i][3];
        *(float4*)&pk[(ty * 4 + i) * HD_ + tx * 4] = o;
    }
    if (tx == 0) {
        float* ps = part_ks + (size_t)(bh * 16 + chunk) * HD_;
        #pragma unroll
        for (int i = 0; i < 4; ++i) ps[ty * 4 + i] = ks[i];
    }
}

// Sum the 16 chunk-partials into final kv [32][4096] and ksum [32][64].
__global__ void kv_reduce2(const float* __restrict__ part_kv,
                           const float* __restrict__ part_ks,
                           float* __restrict__ kv, float* __restrict__ ksum)
{
    const int i = blockIdx.x * 256 + threadIdx.x;
    if (i < 32 * 4096) {
        const int bh = i >> 12, e = i & 4095;
        float s = 0.0f;
        #pragma unroll
        for (int c = 0; c < 16; ++c) s += part_kv[(size_t)(bh * 16 + c) * 4096 + e];
        kv[i] = s;
    }
    if (i < 32 * 64) {
        const int bh = i >> 6, e = i & 63;
        float s = 0.0f;
        #pragma unroll
        for (int c = 0; c < 16; ++c) s += part_ks[(size_t)(bh * 16 + c) * 64 + e];
        ksum[i] = s;
    }
}

// ---------------------------------------------------------------------------
// attn[s][e] = (q[s]·kv[:,e]) / max(q[s]·ksum, 1e-6), per (b,h).
// grid (32, 128): 64 s-rows x 64 e-cols per block. Writes into the dead
// v-columns (1024..1535) of the qkv workspace.
// ---------------------------------------------------------------------------
__global__ __launch_bounds__(256) void apply_attn(
    float* __restrict__ qkv,
    const float* __restrict__ kv,
    const float* __restrict__ ksum)
{
    const int bh = blockIdx.x;
    const int sb = blockIdx.y * 64;
    const int b = bh >> 3, h = bh & 7;

    __shared__ __align__(16) float Qs[64][68];    // [d][s] transposed
    __shared__ __align__(16) float KVs[64][68];   // [d][e]
    __shared__ float ksums[64];
    __shared__ float dens[64];

    const int t  = threadIdx.x;
    const int tx = t & 15, ty = t >> 4;

    {   // stage kv head (4096 floats) + ksum
        const float* kvh = kv + (size_t)bh * 4096;
        #pragma unroll
        for (int i = 0; i < 4; ++i) {
            const int d = (t >> 4) + i * 16;
            const int e = (t & 15) * 4;
            *(float4*)&KVs[d][e] = *(const float4*)&kvh[d * HD_ + e];
        }
        if (t < 16) {
            const float4 kk = *(const float4*)&ksum[bh * HD_ + t * 4];
            ksums[t * 4 + 0] = kk.x; ksums[t * 4 + 1] = kk.y;
            ksums[t * 4 + 2] = kk.z; ksums[t * 4 + 3] = kk.w;
        }
    }
    {   // stage q tile transposed: 64 s x 64 d = 1024 float4, 4 per thread
        const int s_l = t >> 2;
        const float* qrow = qkv + (size_t)(b * S_ + sb + s_l) * QKV_LD + h * HD_;
        #pragma unroll
        for (int i = 0; i < 4; ++i) {
            const int dq = (t & 3) * 4 + i * 16;   // BUGFIX R1: cover d=0..63, was 0..15
            const float4 qv = *(const float4*)&qrow[dq];
            Qs[dq + 0][s_l] = qv.x; Qs[dq + 1][s_l] = qv.y;
            Qs[dq + 2][s_l] = qv.z; Qs[dq + 3][s_l] = qv.w;
        }
    }
    __syncthreads();

    float acc[4][4] = {};
    float den[4] = {};
    #pragma unroll
    for (int d = 0; d < 64; ++d) {
        const float4 a  = *(const float4*)&Qs[d][ty * 4];
        const float4 bv = *(const float4*)&KVs[d][tx * 4];
        acc[0][0] += a.x * bv.x; acc[0][1] += a.x * bv.y; acc[0][2] += a.x * bv.z; acc[0][3] += a.x * bv.w;
        acc[1][0] += a.y * bv.x; acc[1][1] += a.y * bv.y; acc[1][2] += a.y * bv.z; acc[1][3] += a.y * bv.w;
        acc[2][0] += a.z * bv.x; acc[2][1] += a.z * bv.y; acc[2][2] += a.z * bv.z; acc[2][3] += a.z * bv.w;
        acc[3][0] += a.w * bv.x; acc[3][1] += a.w * bv.y; acc[3][2] += a.w * bv.z; acc[3][3] += a.w * bv.w;
        if (tx == 0) {
            const float kd = ksums[d];
            den[0] += a.x * kd; den[1] += a.y * kd; den[2] += a.z * kd; den[3] += a.w * kd;
        }
    }
    if (tx == 0) {
        #pragma unroll
        for (int i = 0; i < 4; ++i) dens[ty * 4 + i] = den[i];
    }
    __syncthreads();

    #pragma unroll
    for (int i = 0; i < 4; ++i) {
        const float dd  = fmaxf(dens[ty * 4 + i], 1e-6f);
        const float inv = 1.0f / dd;
        float4 o;
        o.x = acc[i][0] * inv; o.y = acc[i][1] * inv;
        o.z = acc[i][2] * inv; o.w = acc[i][3] * inv;
        const size_t r = (size_t)(b * S_ + sb + ty * 4 + i);
        *(float4*)&qkv[r * QKV_LD + 2 * D_ + h * HD_ + tx * 4] = o;
    }
}

// ---------------------------------------------------------------------------
extern "C" void kernel_launch(void* const* d_in, const int* in_sizes, int n_in,
                              void* d_out, int out_size, void* d_ws, size_t ws_size,
                              hipStream_t stream)
{
    const float* query        = (const float*)d_in[0];
    // d_in[1] (key), d_in[2] (value) are unused by the reference module.
    const unsigned char* kpm  = (const unsigned char*)d_in[3];
    const float* w_in         = (const float*)d_in[4];
    const float* b_in         = (const float*)d_in[5];
    const float* w_out        = (const float*)d_in[6];
    const float* b_out        = (const float*)d_in[7];
    float* out = (float*)d_out;

    // workspace layout (floats)
    float* qkv     = (float*)d_ws;                         // NROW*1536      (192 MB)
    float* part_kv = qkv + (size_t)NROW * QKV_LD;          // 512*4096       (8 MB)
    float* part_ks = part_kv + (size_t)512 * 4096;         // 512*64
    float* kv      = part_ks + 512 * 64;                   // 32*4096
    float* ksum    = kv + 32 * 4096;                       // 32*64
    int*   flag    = (int*)(ksum + 32 * 64);               // 1

    hipLaunchKernelGGL(detect_mask, dim3(1), dim3(256), 0, stream, kpm, flag);

    // 1) qkv = query @ W_in^T + b_in, fused phi/mask epilogue
    hipLaunchKernelGGL(gemm_nt, dim3(1536 / 64, NROW / 64), dim3(256), 0, stream,
                       query, D_, w_in, D_, b_in, qkv, QKV_LD, D_, 0, kpm, flag);

    // 2) kv = k^T v, k_sum per head (two-stage, no atomics)
    hipLaunchKernelGGL(kv_reduce, dim3(32, 16), dim3(256), 0, stream, qkv, part_kv, part_ks);
    hipLaunchKernelGGL(kv_reduce2, dim3((32 * 4096) / 256), dim3(256), 0, stream,
                       part_kv, part_ks, kv, ksum);

    // 3) attn = (q·kv) / max(q·ksum, 1e-6), into dead v-columns of qkv
    hipLaunchKernelGGL(apply_attn, dim3(32, S_ / 64), dim3(256), 0, stream, qkv, kv, ksum);

    // 4) out = attn @ W_out^T + b_out
    hipLaunchKernelGGL(gemm_nt, dim3(D_ / 64, NROW / 64), dim3(256), 0, stream,
                       qkv + 2 * D_, QKV_LD, w_out, D_, b_out, out, D_, D_, 1,
                       (const unsigned char*)nullptr, (const int*)nullptr);
}

// Round 3
// 971.736 us; speedup vs baseline: 1.7590x; 1.7590x over previous
//
#include <hip/hip_runtime.h>
#include <cstddef>

#define B_   4
#define S_   8192
#define D_   512
#define H_   8
#define HD_  64
#define NROW (B_ * S_)              // 32768
#define NQ   ((size_t)NROW * D_)    // 16777216 elements per q/k/v buffer

typedef __attribute__((ext_vector_type(4))) float  f32x4;
typedef __attribute__((ext_vector_type(8))) short  s16x8;
typedef __attribute__((ext_vector_type(4))) unsigned short u16x4;
typedef __attribute__((ext_vector_type(8))) unsigned short u16x8;

__device__ __forceinline__ float phi_f(float x) {
    return x > 0.0f ? x + 1.0f : expf(x);   // elu(x)+1
}
__device__ __forceinline__ float bf2f(unsigned short u) {
    return __uint_as_float(((unsigned int)u) << 16);
}
__device__ __forceinline__ unsigned short f2bf(float f) {
    unsigned int u = __float_as_uint(f);
    u += 0x7fffu + ((u >> 16) & 1u);        // round-to-nearest-even
    return (unsigned short)(u >> 16);
}

#define GLOBAL_AS(p) ((const __attribute__((address_space(1))) void*)(p))
#define LDS_AS(p)    ((__attribute__((address_space(3))) void*)(p))

// ---------------------------------------------------------------------------
// Mask layout detector: 1 = byte-per-element (bool), 0 = 4-byte layout.
// ---------------------------------------------------------------------------
__global__ void detect_mask(const unsigned char* __restrict__ m, int* __restrict__ flag) {
    __shared__ int sany;
    if (threadIdx.x == 0) sany = 0;
    __syncthreads();
    int any = 0;
    for (int i = 1 + 4 * (int)threadIdx.x; i < NROW; i += 4 * 256) any |= m[i];
    if (any) atomicOr(&sany, 1);
    __syncthreads();
    if (threadIdx.x == 0) *flag = sany ? 1 : 0;
}

// ---------------------------------------------------------------------------
// Convert query/w_in/w_out -> bf16; mask -> float (1.0 keep / 0.0 ignore).
// Grid: 16384 x 256 (one thread per 4 query floats).
// ---------------------------------------------------------------------------
__global__ __launch_bounds__(256) void convert_all(
    const float* __restrict__ q,  unsigned short* __restrict__ qb,
    const float* __restrict__ wi, unsigned short* __restrict__ wib,
    const float* __restrict__ wo, unsigned short* __restrict__ wob,
    const unsigned char* __restrict__ kpm, const int* __restrict__ flag,
    float* __restrict__ fmask)
{
    const size_t i = (size_t)blockIdx.x * 256 + threadIdx.x;
    {   // query: 16777216 / 4 = 4194304 threads exactly
        const float4 v = *(const float4*)&q[i * 4];
        u16x4 o; o.x = f2bf(v.x); o.y = f2bf(v.y); o.z = f2bf(v.z); o.w = f2bf(v.w);
        *(u16x4*)&qb[i * 4] = o;
    }
    if (i < 786432 / 4) {
        const float4 v = *(const float4*)&wi[i * 4];
        u16x4 o; o.x = f2bf(v.x); o.y = f2bf(v.y); o.z = f2bf(v.z); o.w = f2bf(v.w);
        *(u16x4*)&wib[i * 4] = o;
    }
    if (i < 262144 / 4) {
        const float4 v = *(const float4*)&wo[i * 4];
        u16x4 o; o.x = f2bf(v.x); o.y = f2bf(v.y); o.z = f2bf(v.z); o.w = f2bf(v.w);
        *(u16x4*)&wob[i * 4] = o;
    }
    if (i < NROW) {
        const bool ignore = (*flag) ? (kpm[i] != 0) : (((const int*)kpm)[i] != 0);
        fmask[i] = ignore ? 0.0f : 1.0f;
    }
}

// ---------------------------------------------------------------------------
// bf16 MFMA GEMM (m97 recipe): C[m][n] = sum_k A[m][k]*B[n][k] + bias[n].
// A (M,512) bf16 row-major, B (N,512) bf16 row-major (weights are (N,K)).
// 128x128 tile, BK=32, 256 thr = 2x2 waves, each wave 64x64 via 4x4 frags of
// v_mfma_f32_16x16x32_bf16. Staging via global_load_lds width=16 (unpadded
// k-contig LDS layout -- required by the wave-uniform-base+lane*16 rule).
// mode 0: in-proj epilogue -> phi / phi*mask / *mask into q/k/v bf16 buffers.
// mode 1: out-proj epilogue -> fp32 to Cout.
// ---------------------------------------------------------------------------
__global__ __launch_bounds__(256) void gemm_mfma(
    const unsigned short* __restrict__ A,  int lda,
    const unsigned short* __restrict__ Bw, int ldb,
    const float* __restrict__ bias, int K, int mode,
    const float* __restrict__ fmask,
    unsigned short* __restrict__ Cq,
    unsigned short* __restrict__ Ck,
    unsigned short* __restrict__ Cv,
    float* __restrict__ Cout)
{
    __shared__ __align__(16) unsigned short As[128 * 32];  // [m][k], 64B rows
    __shared__ __align__(16) unsigned short Bs[128 * 32];  // [n][k]
    __shared__ float fm[128];

    const int t    = threadIdx.x;
    const int lane = t & 63;
    const int wave = t >> 6;            // 0..3
    const int wm   = wave & 1;          // wave m-offset (x64)
    const int wn   = wave >> 1;         // wave n-offset (x64)
    const int m0   = blockIdx.y * 128;
    const int n0   = blockIdx.x * 128;

    if (mode == 0 && t < 128) fm[t] = fmask[m0 + t];

    f32x4 acc[4][4] = {};

    const int sr = lane >> 2;           // staging row-in-16 group
    const int sk = (lane & 3) * 8;      // staging k element offset (16B chunks)

    for (int k0 = 0; k0 < K; k0 += 32) {
        __syncthreads();                // LDS free to overwrite
        #pragma unroll
        for (int j = 0; j < 2; ++j) {   // A: wave covers rows [wave*32, +32)
            const int row = wave * 32 + j * 16;
            const unsigned short* g = A + (size_t)(m0 + row + sr) * lda + k0 + sk;
            __builtin_amdgcn_global_load_lds(GLOBAL_AS(g), LDS_AS(&As[row * 32]), 16, 0, 0);
        }
        #pragma unroll
        for (int j = 0; j < 2; ++j) {   // B
            const int row = wave * 32 + j * 16;
            const unsigned short* g = Bw + (size_t)(n0 + row + sr) * ldb + k0 + sk;
            __builtin_amdgcn_global_load_lds(GLOBAL_AS(g), LDS_AS(&Bs[row * 32]), 16, 0, 0);
        }
        __syncthreads();                // staging complete (vmcnt drained at barrier)

        const int fr = lane & 15;       // m (or n) within 16
        const int fk = (lane >> 4) * 8; // k offset within 32
        s16x8 af[4], bf[4];
        #pragma unroll
        for (int i = 0; i < 4; ++i)
            af[i] = *(const s16x8*)&As[(wm * 64 + i * 16 + fr) * 32 + fk];
        #pragma unroll
        for (int j = 0; j < 4; ++j)
            bf[j] = *(const s16x8*)&Bs[(wn * 64 + j * 16 + fr) * 32 + fk];
        #pragma unroll
        for (int i = 0; i < 4; ++i)
            #pragma unroll
            for (int j = 0; j < 4; ++j)
                acc[i][j] = __builtin_amdgcn_mfma_f32_16x16x32_bf16(af[i], bf[j], acc[i][j], 0, 0, 0);
    }

    // Epilogue. C/D layout: n = lane&15, m = (lane>>4)*4 + reg.
    const int col  = lane & 15;
    const int rowq = (lane >> 4) * 4;
    float bj[4];
    #pragma unroll
    for (int j = 0; j < 4; ++j) bj[j] = bias[n0 + wn * 64 + j * 16 + col];

    if (mode == 1) {
        #pragma unroll
        for (int i = 0; i < 4; ++i)
            #pragma unroll
            for (int r = 0; r < 4; ++r) {
                const int m = m0 + wm * 64 + i * 16 + rowq + r;
                #pragma unroll
                for (int j = 0; j < 4; ++j) {
                    const int n = n0 + wn * 64 + j * 16 + col;
                    Cout[(size_t)m * D_ + n] = acc[i][j][r] + bj[j];
                }
            }
    } else {
        const int region = n0 >> 9;     // 0:q 1:k 2:v (BN=128 divides 512)
        unsigned short* Cb = region == 0 ? Cq : (region == 1 ? Ck : Cv);
        #pragma unroll
        for (int i = 0; i < 4; ++i)
            #pragma unroll
            for (int r = 0; r < 4; ++r) {
                const int ml = wm * 64 + i * 16 + rowq + r;
                const int m  = m0 + ml;
                const float mk = fm[ml];
                #pragma unroll
                for (int j = 0; j < 4; ++j) {
                    const int n  = (n0 & 511) + wn * 64 + j * 16 + col;
                    float v = acc[i][j][r] + bj[j];
                    if (region == 0)      v = phi_f(v);
                    else if (region == 1) v = phi_f(v) * mk;
                    else                  v = v * mk;
                    Cb[(size_t)m * D_ + n] = f2bf(v);
                }
            }
    }
}

// ---------------------------------------------------------------------------
// Per (head, S-chunk) partial kv = k^T v (64x64) and k_sum. bf16 in, fp32 out.
// ---------------------------------------------------------------------------
__global__ __launch_bounds__(256) void kv_reduce(
    const unsigned short* __restrict__ kbuf,   // [NROW][512] bf16
    const unsigned short* __restrict__ vbuf,
    float* __restrict__ part_kv,               // [512][4096]
    float* __restrict__ part_ks)               // [512][64]
{
    const int bh = blockIdx.x, chunk = blockIdx.y;
    const int b = bh >> 3, h = bh & 7;

    __shared__ __align__(16) float Ks[16][64];
    __shared__ __align__(16) float Vs[16][64];

    const int t  = threadIdx.x;
    const int tx = t & 15, ty = t >> 4;
    const int ls = t >> 4;
    const int lc = (t & 15) * 4;

    const unsigned short* kb = kbuf + (size_t)b * S_ * D_ + h * HD_;
    const unsigned short* vb = vbuf + (size_t)b * S_ * D_ + h * HD_;

    float acc[4][4] = {};
    float ks[4] = {};
    const int s0 = chunk * (S_ / 16);

    for (int it = 0; it < S_ / 16; it += 16) {
        const size_t s = (size_t)(s0 + it + ls);
        const u16x4 kk = *(const u16x4*)&kb[s * D_ + lc];
        const u16x4 vv = *(const u16x4*)&vb[s * D_ + lc];
        Ks[ls][lc + 0] = bf2f(kk.x); Ks[ls][lc + 1] = bf2f(kk.y);
        Ks[ls][lc + 2] = bf2f(kk.z); Ks[ls][lc + 3] = bf2f(kk.w);
        Vs[ls][lc + 0] = bf2f(vv.x); Vs[ls][lc + 1] = bf2f(vv.y);
        Vs[ls][lc + 2] = bf2f(vv.z); Vs[ls][lc + 3] = bf2f(vv.w);
        __syncthreads();
        #pragma unroll
        for (int ss = 0; ss < 16; ++ss) {
            const float4 a = *(const float4*)&Ks[ss][ty * 4];
            const float4 v = *(const float4*)&Vs[ss][tx * 4];
            acc[0][0] += a.x * v.x; acc[0][1] += a.x * v.y; acc[0][2] += a.x * v.z; acc[0][3] += a.x * v.w;
            acc[1][0] += a.y * v.x; acc[1][1] += a.y * v.y; acc[1][2] += a.y * v.z; acc[1][3] += a.y * v.w;
            acc[2][0] += a.z * v.x; acc[2][1] += a.z * v.y; acc[2][2] += a.z * v.z; acc[2][3] += a.z * v.w;
            acc[3][0] += a.w * v.x; acc[3][1] += a.w * v.y; acc[3][2] += a.w * v.z; acc[3][3] += a.w * v.w;
            if (tx == 0) { ks[0] += a.x; ks[1] += a.y; ks[2] += a.z; ks[3] += a.w; }
        }
        __syncthreads();
    }

    float* pk = part_kv + (size_t)(bh * 16 + chunk) * 4096;
    #pragma unroll
    for (int i = 0; i < 4; ++i) {
        float4 o; o.x = acc[i][0]; o.y = acc[i][1]; o.z = acc[i][2]; o.w = acc[i][3];
        *(float4*)&pk[(ty * 4 + i) * HD_ + tx * 4] = o;
    }
    if (tx == 0) {
        float* ps = part_ks + (size_t)(bh * 16 + chunk) * HD_;
        #pragma unroll
        for (int i = 0; i < 4; ++i) ps[ty * 4 + i] = ks[i];
    }
}

__global__ void kv_reduce2(const float* __restrict__ part_kv,
                           const float* __restrict__ part_ks,
                           float* __restrict__ kv, float* __restrict__ ksum)
{
    const int i = blockIdx.x * 256 + threadIdx.x;
    if (i < 32 * 4096) {
        const int bh = i >> 12, e = i & 4095;
        float s = 0.0f;
        #pragma unroll
        for (int c = 0; c < 16; ++c) s += part_kv[(size_t)(bh * 16 + c) * 4096 + e];
        kv[i] = s;
    }
    if (i < 32 * 64) {
        const int bh = i >> 6, e = i & 63;
        float s = 0.0f;
        #pragma unroll
        for (int c = 0; c < 16; ++c) s += part_ks[(size_t)(bh * 16 + c) * 64 + e];
        ksum[i] = s;
    }
}

// ---------------------------------------------------------------------------
// attn[s][e] = (q[s]·kv[:,e]) / max(q[s]·ksum, 1e-6).  q bf16 in, attn bf16 out.
// ---------------------------------------------------------------------------
__global__ __launch_bounds__(256) void apply_attn(
    const unsigned short* __restrict__ qbuf,   // [NROW][512] bf16 (phi'd)
    const float* __restrict__ kv,
    const float* __restrict__ ksum,
    unsigned short* __restrict__ attnb)        // [NROW][512] bf16
{
    const int bh = blockIdx.x;
    const int sb = blockIdx.y * 64;
    const int b = bh >> 3, h = bh & 7;

    __shared__ __align__(16) float Qs[64][68];    // [d][s] transposed
    __shared__ __align__(16) float KVs[64][68];   // [d][e]
    __shared__ float ksums[64];
    __shared__ float dens[64];

    const int t  = threadIdx.x;
    const int tx = t & 15, ty = t >> 4;

    {   // stage kv head + ksum
        const float* kvh = kv + (size_t)bh * 4096;
        #pragma unroll
        for (int i = 0; i < 4; ++i) {
            const int d = (t >> 4) + i * 16;
            const int e = (t & 15) * 4;
            *(float4*)&KVs[d][e] = *(const float4*)&kvh[d * HD_ + e];
        }
        if (t < 16) {
            const float4 kk = *(const float4*)&ksum[bh * HD_ + t * 4];
            ksums[t * 4 + 0] = kk.x; ksums[t * 4 + 1] = kk.y;
            ksums[t * 4 + 2] = kk.z; ksums[t * 4 + 3] = kk.w;
        }
    }
    {   // stage q tile transposed: each thread 16 contiguous bf16 of one row
        const int s_l = t >> 2;
        const int dq  = (t & 3) * 16;
        const unsigned short* qrow = qbuf + (size_t)(b * S_ + sb + s_l) * D_ + h * HD_;
        const u16x8 q0 = *(const u16x8*)&qrow[dq];
        const u16x8 q1 = *(const u16x8*)&qrow[dq + 8];
        #pragma unroll
        for (int e = 0; e < 8; ++e) Qs[dq + e][s_l] = bf2f(q0[e]);
        #pragma unroll
        for (int e = 0; e < 8; ++e) Qs[dq + 8 + e][s_l] = bf2f(q1[e]);
    }
    __syncthreads();

    float acc[4][4] = {};
    float den[4] = {};
    #pragma unroll
    for (int d = 0; d < 64; ++d) {
        const float4 a  = *(const float4*)&Qs[d][ty * 4];
        const float4 bv = *(const float4*)&KVs[d][tx * 4];
        acc[0][0] += a.x * bv.x; acc[0][1] += a.x * bv.y; acc[0][2] += a.x * bv.z; acc[0][3] += a.x * bv.w;
        acc[1][0] += a.y * bv.x; acc[1][1] += a.y * bv.y; acc[1][2] += a.y * bv.z; acc[1][3] += a.y * bv.w;
        acc[2][0] += a.z * bv.x; acc[2][1] += a.z * bv.y; acc[2][2] += a.z * bv.z; acc[2][3] += a.z * bv.w;
        acc[3][0] += a.w * bv.x; acc[3][1] += a.w * bv.y; acc[3][2] += a.w * bv.z; acc[3][3] += a.w * bv.w;
        if (tx == 0) {
            const float kd = ksums[d];
            den[0] += a.x * kd; den[1] += a.y * kd; den[2] += a.z * kd; den[3] += a.w * kd;
        }
    }
    if (tx == 0) {
        #pragma unroll
        for (int i = 0; i < 4; ++i) dens[ty * 4 + i] = den[i];
    }
    __syncthreads();

    #pragma unroll
    for (int i = 0; i < 4; ++i) {
        const float inv = 1.0f / fmaxf(dens[ty * 4 + i], 1e-6f);
        u16x4 o;
        o.x = f2bf(acc[i][0] * inv); o.y = f2bf(acc[i][1] * inv);
        o.z = f2bf(acc[i][2] * inv); o.w = f2bf(acc[i][3] * inv);
        const size_t r = (size_t)(b * S_ + sb + ty * 4 + i);
        *(u16x4*)&attnb[r * D_ + h * HD_ + tx * 4] = o;
    }
}

// ---------------------------------------------------------------------------
extern "C" void kernel_launch(void* const* d_in, const int* in_sizes, int n_in,
                              void* d_out, int out_size, void* d_ws, size_t ws_size,
                              hipStream_t stream)
{
    const float* query       = (const float*)d_in[0];
    const unsigned char* kpm = (const unsigned char*)d_in[3];
    const float* w_in        = (const float*)d_in[4];
    const float* b_in        = (const float*)d_in[5];
    const float* w_out       = (const float*)d_in[6];
    const float* b_out       = (const float*)d_in[7];
    float* out = (float*)d_out;

    // workspace layout
    unsigned short* qb    = (unsigned short*)d_ws;          // query bf16     33.5 MB
    unsigned short* qphi  = qb    + NQ;                     // phi(q)         33.5 MB
    unsigned short* kpb   = qphi  + NQ;                     // phi(k)*mask    33.5 MB
    unsigned short* vmb   = kpb   + NQ;                     // v*mask         33.5 MB
    unsigned short* attnb = vmb   + NQ;                     // attn           33.5 MB
    unsigned short* wib   = attnb + NQ;                     // w_in bf16       1.6 MB
    unsigned short* wob   = wib   + 1536 * 512;             // w_out bf16      0.5 MB
    float* fmask   = (float*)(wob + 512 * 512);             // 128 KB
    float* part_kv = fmask + NROW;                          // 8.4 MB
    float* part_ks = part_kv + (size_t)512 * 4096;
    float* kv      = part_ks + 512 * 64;
    float* ksum    = kv + 32 * 4096;
    int*   flag    = (int*)(ksum + 32 * 64);

    hipLaunchKernelGGL(detect_mask, dim3(1), dim3(256), 0, stream, kpm, flag);
    hipLaunchKernelGGL(convert_all, dim3(16384), dim3(256), 0, stream,
                       query, qb, w_in, wib, w_out, wob, kpm, flag, fmask);

    // in-proj: M=32768, N=1536, K=512; epilogue -> qphi/kpb/vmb (bf16)
    hipLaunchKernelGGL(gemm_mfma, dim3(1536 / 128, NROW / 128), dim3(256), 0, stream,
                       qb, D_, wib, D_, b_in, D_, 0, fmask,
                       qphi, kpb, vmb, (float*)nullptr);

    hipLaunchKernelGGL(kv_reduce, dim3(32, 16), dim3(256), 0, stream, kpb, vmb, part_kv, part_ks);
    hipLaunchKernelGGL(kv_reduce2, dim3((32 * 4096) / 256), dim3(256), 0, stream,
                       part_kv, part_ks, kv, ksum);
    hipLaunchKernelGGL(apply_attn, dim3(32, S_ / 64), dim3(256), 0, stream, qphi, kv, ksum, attnb);

    // out-proj: M=32768, N=512, K=512 -> fp32 d_out
    hipLaunchKernelGGL(gemm_mfma, dim3(512 / 128, NROW / 128), dim3(256), 0, stream,
                       attnb, D_, wob, D_, b_out, D_, 1, (const float*)nullptr,
                       (unsigned short*)nullptr, (unsigned short*)nullptr,
                       (unsigned short*)nullptr, out);
}

// Round 4
// 407.271 us; speedup vs baseline: 4.1969x; 2.3860x over previous
//
#include <hip/hip_runtime.h>
#include <cstddef>

#define B_   4
#define S_   8192
#define D_   512
#define H_   8
#define HD_  64
#define NROW (B_ * S_)              // 32768
#define NQ   ((size_t)NROW * D_)    // 16777216 elements per q/k/v buffer

typedef __attribute__((ext_vector_type(4))) float  f32x4;
typedef __attribute__((ext_vector_type(8))) short  s16x8;
typedef __attribute__((ext_vector_type(4))) unsigned short u16x4;
typedef __attribute__((ext_vector_type(8))) unsigned short u16x8;

__device__ __forceinline__ float phi_f(float x) {
    return x > 0.0f ? x + 1.0f : expf(x);   // elu(x)+1
}
__device__ __forceinline__ float bf2f(unsigned short u) {
    return __uint_as_float(((unsigned int)u) << 16);
}
__device__ __forceinline__ unsigned short f2bf(float f) {
    unsigned int u = __float_as_uint(f);
    u += 0x7fffu + ((u >> 16) & 1u);        // round-to-nearest-even
    return (unsigned short)(u >> 16);
}

#define GLOBAL_AS(p) ((const __attribute__((address_space(1))) void*)(p))
#define LDS_AS(p)    ((__attribute__((address_space(3))) void*)(p))

// ---------------------------------------------------------------------------
// Mask layout detector: 1 = byte-per-element (bool), 0 = 4-byte layout.
// ---------------------------------------------------------------------------
__global__ void detect_mask(const unsigned char* __restrict__ m, int* __restrict__ flag) {
    __shared__ int sany;
    if (threadIdx.x == 0) sany = 0;
    __syncthreads();
    int any = 0;
    for (int i = 1 + 4 * (int)threadIdx.x; i < NROW; i += 4 * 256) any |= m[i];
    if (any) atomicOr(&sany, 1);
    __syncthreads();
    if (threadIdx.x == 0) *flag = sany ? 1 : 0;
}

// ---------------------------------------------------------------------------
// Convert query/w_in/w_out -> bf16; mask -> float (1.0 keep / 0.0 ignore).
// ---------------------------------------------------------------------------
__global__ __launch_bounds__(256) void convert_all(
    const float* __restrict__ q,  unsigned short* __restrict__ qb,
    const float* __restrict__ wi, unsigned short* __restrict__ wib,
    const float* __restrict__ wo, unsigned short* __restrict__ wob,
    const unsigned char* __restrict__ kpm, const int* __restrict__ flag,
    float* __restrict__ fmask)
{
    const size_t i = (size_t)blockIdx.x * 256 + threadIdx.x;
    {   // query: 16777216 / 4 = 4194304 threads exactly
        const float4 v = *(const float4*)&q[i * 4];
        u16x4 o; o.x = f2bf(v.x); o.y = f2bf(v.y); o.z = f2bf(v.z); o.w = f2bf(v.w);
        *(u16x4*)&qb[i * 4] = o;
    }
    if (i < 786432 / 4) {
        const float4 v = *(const float4*)&wi[i * 4];
        u16x4 o; o.x = f2bf(v.x); o.y = f2bf(v.y); o.z = f2bf(v.z); o.w = f2bf(v.w);
        *(u16x4*)&wib[i * 4] = o;
    }
    if (i < 262144 / 4) {
        const float4 v = *(const float4*)&wo[i * 4];
        u16x4 o; o.x = f2bf(v.x); o.y = f2bf(v.y); o.z = f2bf(v.z); o.w = f2bf(v.w);
        *(u16x4*)&wob[i * 4] = o;
    }
    if (i < NROW) {
        const bool ignore = (*flag) ? (kpm[i] != 0) : (((const int*)kpm)[i] != 0);
        fmask[i] = ignore ? 0.0f : 1.0f;
    }
}

// ---------------------------------------------------------------------------
// bf16 MFMA GEMM (m97 recipe): C[m][n] = sum_k A[m][k]*B[n][k] + bias[n].
// 128x128 tile, BK=32, 256 thr = 2x2 waves, 4x4 frags of 16x16x32_bf16,
// global_load_lds width=16, unpadded k-contig LDS.
// mode 0: in-proj epilogue -> phi / phi*mask / *mask into q/k/v bf16 buffers.
// mode 1: out-proj epilogue -> fp32 to Cout.
// ---------------------------------------------------------------------------
__global__ __launch_bounds__(256) void gemm_mfma(
    const unsigned short* __restrict__ A,  int lda,
    const unsigned short* __restrict__ Bw, int ldb,
    const float* __restrict__ bias, int K, int mode,
    const float* __restrict__ fmask,
    unsigned short* __restrict__ Cq,
    unsigned short* __restrict__ Ck,
    unsigned short* __restrict__ Cv,
    float* __restrict__ Cout)
{
    __shared__ __align__(16) unsigned short As[128 * 32];  // [m][k], 64B rows
    __shared__ __align__(16) unsigned short Bs[128 * 32];  // [n][k]
    __shared__ float fm[128];

    const int t    = threadIdx.x;
    const int lane = t & 63;
    const int wave = t >> 6;            // 0..3
    const int wm   = wave & 1;          // wave m-offset (x64)
    const int wn   = wave >> 1;         // wave n-offset (x64)
    const int m0   = blockIdx.y * 128;
    const int n0   = blockIdx.x * 128;

    if (mode == 0 && t < 128) fm[t] = fmask[m0 + t];

    f32x4 acc[4][4] = {};

    const int sr = lane >> 2;           // staging row-in-16 group
    const int sk = (lane & 3) * 8;      // staging k element offset (16B chunks)

    for (int k0 = 0; k0 < K; k0 += 32) {
        __syncthreads();                // LDS free to overwrite
        #pragma unroll
        for (int j = 0; j < 2; ++j) {   // A: wave covers rows [wave*32, +32)
            const int row = wave * 32 + j * 16;
            const unsigned short* g = A + (size_t)(m0 + row + sr) * lda + k0 + sk;
            __builtin_amdgcn_global_load_lds(GLOBAL_AS(g), LDS_AS(&As[row * 32]), 16, 0, 0);
        }
        #pragma unroll
        for (int j = 0; j < 2; ++j) {   // B
            const int row = wave * 32 + j * 16;
            const unsigned short* g = Bw + (size_t)(n0 + row + sr) * ldb + k0 + sk;
            __builtin_amdgcn_global_load_lds(GLOBAL_AS(g), LDS_AS(&Bs[row * 32]), 16, 0, 0);
        }
        __syncthreads();                // staging complete (vmcnt drained at barrier)

        const int fr = lane & 15;       // m (or n) within 16
        const int fk = (lane >> 4) * 8; // k offset within 32
        s16x8 af[4], bf[4];
        #pragma unroll
        for (int i = 0; i < 4; ++i)
            af[i] = *(const s16x8*)&As[(wm * 64 + i * 16 + fr) * 32 + fk];
        #pragma unroll
        for (int j = 0; j < 4; ++j)
            bf[j] = *(const s16x8*)&Bs[(wn * 64 + j * 16 + fr) * 32 + fk];
        #pragma unroll
        for (int i = 0; i < 4; ++i)
            #pragma unroll
            for (int j = 0; j < 4; ++j)
                acc[i][j] = __builtin_amdgcn_mfma_f32_16x16x32_bf16(af[i], bf[j], acc[i][j], 0, 0, 0);
    }

    // Epilogue. C/D layout: n = lane&15, m = (lane>>4)*4 + reg.
    const int col  = lane & 15;
    const int rowq = (lane >> 4) * 4;
    float bj[4];
    #pragma unroll
    for (int j = 0; j < 4; ++j) bj[j] = bias[n0 + wn * 64 + j * 16 + col];

    if (mode == 1) {
        #pragma unroll
        for (int i = 0; i < 4; ++i)
            #pragma unroll
            for (int r = 0; r < 4; ++r) {
                const int m = m0 + wm * 64 + i * 16 + rowq + r;
                #pragma unroll
                for (int j = 0; j < 4; ++j) {
                    const int n = n0 + wn * 64 + j * 16 + col;
                    Cout[(size_t)m * D_ + n] = acc[i][j][r] + bj[j];
                }
            }
    } else {
        const int region = n0 >> 9;     // 0:q 1:k 2:v (BN=128 divides 512)
        unsigned short* Cb = region == 0 ? Cq : (region == 1 ? Ck : Cv);
        #pragma unroll
        for (int i = 0; i < 4; ++i)
            #pragma unroll
            for (int r = 0; r < 4; ++r) {
                const int ml = wm * 64 + i * 16 + rowq + r;
                const int m  = m0 + ml;
                const float mk = fm[ml];
                #pragma unroll
                for (int j = 0; j < 4; ++j) {
                    const int n  = (n0 & 511) + wn * 64 + j * 16 + col;
                    float v = acc[i][j][r] + bj[j];
                    if (region == 0)      v = phi_f(v);
                    else if (region == 1) v = phi_f(v) * mk;
                    else                  v = v * mk;
                    Cb[(size_t)m * D_ + n] = f2bf(v);
                }
            }
    }
}

// ---------------------------------------------------------------------------
// Per (head, S-chunk) partial kv = k^T v (64x64) and k_sum. bf16 in, fp32 out.
// ---------------------------------------------------------------------------
__global__ __launch_bounds__(256) void kv_reduce(
    const unsigned short* __restrict__ kbuf,   // [NROW][512] bf16
    const unsigned short* __restrict__ vbuf,
    float* __restrict__ part_kv,               // [512][4096]
    float* __restrict__ part_ks)               // [512][64]
{
    const int bh = blockIdx.x, chunk = blockIdx.y;
    const int b = bh >> 3, h = bh & 7;

    __shared__ __align__(16) float Ks[16][64];
    __shared__ __align__(16) float Vs[16][64];

    const int t  = threadIdx.x;
    const int tx = t & 15, ty = t >> 4;
    const int ls = t >> 4;
    const int lc = (t & 15) * 4;

    const unsigned short* kb = kbuf + (size_t)b * S_ * D_ + h * HD_;
    const unsigned short* vb = vbuf + (size_t)b * S_ * D_ + h * HD_;

    float acc[4][4] = {};
    float ks[4] = {};
    const int s0 = chunk * (S_ / 16);

    for (int it = 0; it < S_ / 16; it += 16) {
        const size_t s = (size_t)(s0 + it + ls);
        const u16x4 kk = *(const u16x4*)&kb[s * D_ + lc];
        const u16x4 vv = *(const u16x4*)&vb[s * D_ + lc];
        Ks[ls][lc + 0] = bf2f(kk.x); Ks[ls][lc + 1] = bf2f(kk.y);
        Ks[ls][lc + 2] = bf2f(kk.z); Ks[ls][lc + 3] = bf2f(kk.w);
        Vs[ls][lc + 0] = bf2f(vv.x); Vs[ls][lc + 1] = bf2f(vv.y);
        Vs[ls][lc + 2] = bf2f(vv.z); Vs[ls][lc + 3] = bf2f(vv.w);
        __syncthreads();
        #pragma unroll
        for (int ss = 0; ss < 16; ++ss) {
            const float4 a = *(const float4*)&Ks[ss][ty * 4];
            const float4 v = *(const float4*)&Vs[ss][tx * 4];
            acc[0][0] += a.x * v.x; acc[0][1] += a.x * v.y; acc[0][2] += a.x * v.z; acc[0][3] += a.x * v.w;
            acc[1][0] += a.y * v.x; acc[1][1] += a.y * v.y; acc[1][2] += a.y * v.z; acc[1][3] += a.y * v.w;
            acc[2][0] += a.z * v.x; acc[2][1] += a.z * v.y; acc[2][2] += a.z * v.z; acc[2][3] += a.z * v.w;
            acc[3][0] += a.w * v.x; acc[3][1] += a.w * v.y; acc[3][2] += a.w * v.z; acc[3][3] += a.w * v.w;
            if (tx == 0) { ks[0] += a.x; ks[1] += a.y; ks[2] += a.z; ks[3] += a.w; }
        }
        __syncthreads();
    }

    float* pk = part_kv + (size_t)(bh * 16 + chunk) * 4096;
    #pragma unroll
    for (int i = 0; i < 4; ++i) {
        float4 o; o.x = acc[i][0]; o.y = acc[i][1]; o.z = acc[i][2]; o.w = acc[i][3];
        *(float4*)&pk[(ty * 4 + i) * HD_ + tx * 4] = o;
    }
    if (tx == 0) {
        float* ps = part_ks + (size_t)(bh * 16 + chunk) * HD_;
        #pragma unroll
        for (int i = 0; i < 4; ++i) ps[ty * 4 + i] = ks[i];
    }
}

__global__ void kv_reduce2(const float* __restrict__ part_kv,
                           const float* __restrict__ part_ks,
                           float* __restrict__ kv, float* __restrict__ ksum)
{
    const int i = blockIdx.x * 256 + threadIdx.x;
    if (i < 32 * 4096) {
        const int bh = i >> 12, e = i & 4095;
        float s = 0.0f;
        #pragma unroll
        for (int c = 0; c < 16; ++c) s += part_kv[(size_t)(bh * 16 + c) * 4096 + e];
        kv[i] = s;
    }
    if (i < 32 * 64) {
        const int bh = i >> 6, e = i & 63;
        float s = 0.0f;
        #pragma unroll
        for (int c = 0; c < 16; ++c) s += part_ks[(size_t)(bh * 16 + c) * 64 + e];
        ksum[i] = s;
    }
}

// ---------------------------------------------------------------------------
// attn[s][e] = (q[s]·kv[:,e]) / max(q[s]·ksum, 1e-6).  q bf16 in, attn bf16 out.
// ---------------------------------------------------------------------------
__global__ __launch_bounds__(256) void apply_attn(
    const unsigned short* __restrict__ qbuf,   // [NROW][512] bf16 (phi'd)
    const float* __restrict__ kv,
    const float* __restrict__ ksum,
    unsigned short* __restrict__ attnb)        // [NROW][512] bf16
{
    const int bh = blockIdx.x;
    const int sb = blockIdx.y * 64;
    const int b = bh >> 3, h = bh & 7;

    __shared__ __align__(16) float Qs[64][68];    // [d][s] transposed
    __shared__ __align__(16) float KVs[64][68];   // [d][e]
    __shared__ float ksums[64];
    __shared__ float dens[64];

    const int t  = threadIdx.x;
    const int tx = t & 15, ty = t >> 4;

    {   // stage kv head + ksum
        const float* kvh = kv + (size_t)bh * 4096;
        #pragma unroll
        for (int i = 0; i < 4; ++i) {
            const int d = (t >> 4) + i * 16;
            const int e = (t & 15) * 4;
            *(float4*)&KVs[d][e] = *(const float4*)&kvh[d * HD_ + e];
        }
        if (t < 16) {
            const float4 kk = *(const float4*)&ksum[bh * HD_ + t * 4];
            ksums[t * 4 + 0] = kk.x; ksums[t * 4 + 1] = kk.y;
            ksums[t * 4 + 2] = kk.z; ksums[t * 4 + 3] = kk.w;
        }
    }
    {   // stage q tile transposed: each thread 16 contiguous bf16 of one row
        const int s_l = t >> 2;
        const int dq  = (t & 3) * 16;
        const unsigned short* qrow = qbuf + (size_t)(b * S_ + sb + s_l) * D_ + h * HD_;
        const u16x8 q0 = *(const u16x8*)&qrow[dq];
        const u16x8 q1 = *(const u16x8*)&qrow[dq + 8];
        #pragma unroll
        for (int e = 0; e < 8; ++e) Qs[dq + e][s_l] = bf2f(q0[e]);
        #pragma unroll
        for (int e = 0; e < 8; ++e) Qs[dq + 8 + e][s_l] = bf2f(q1[e]);
    }
    __syncthreads();

    float acc[4][4] = {};
    float den[4] = {};
    // R4 FIX: was `#pragma unroll` (full 64x) -> compiler hoisted ~128
    // ds_read_b128, blew past 256 VGPRs, spilled ~1.8 KB/thread to scratch
    // = ~1.9 GB of HBM traffic (FETCH 768 MB / WRITE 1.2 GB observed).
    // Partial unroll keeps ILP with bounded live ranges.
    #pragma unroll 4
    for (int d = 0; d < 64; ++d) {
        const float4 a  = *(const float4*)&Qs[d][ty * 4];
        const float4 bv = *(const float4*)&KVs[d][tx * 4];
        acc[0][0] += a.x * bv.x; acc[0][1] += a.x * bv.y; acc[0][2] += a.x * bv.z; acc[0][3] += a.x * bv.w;
        acc[1][0] += a.y * bv.x; acc[1][1] += a.y * bv.y; acc[1][2] += a.y * bv.z; acc[1][3] += a.y * bv.w;
        acc[2][0] += a.z * bv.x; acc[2][1] += a.z * bv.y; acc[2][2] += a.z * bv.z; acc[2][3] += a.z * bv.w;
        acc[3][0] += a.w * bv.x; acc[3][1] += a.w * bv.y; acc[3][2] += a.w * bv.z; acc[3][3] += a.w * bv.w;
        if (tx == 0) {
            const float kd = ksums[d];
            den[0] += a.x * kd; den[1] += a.y * kd; den[2] += a.z * kd; den[3] += a.w * kd;
        }
    }
    if (tx == 0) {
        #pragma unroll
        for (int i = 0; i < 4; ++i) dens[ty * 4 + i] = den[i];
    }
    __syncthreads();

    #pragma unroll
    for (int i = 0; i < 4; ++i) {
        const float inv = 1.0f / fmaxf(dens[ty * 4 + i], 1e-6f);
        u16x4 o;
        o.x = f2bf(acc[i][0] * inv); o.y = f2bf(acc[i][1] * inv);
        o.z = f2bf(acc[i][2] * inv); o.w = f2bf(acc[i][3] * inv);
        const size_t r = (size_t)(b * S_ + sb + ty * 4 + i);
        *(u16x4*)&attnb[r * D_ + h * HD_ + tx * 4] = o;
    }
}

// ---------------------------------------------------------------------------
extern "C" void kernel_launch(void* const* d_in, const int* in_sizes, int n_in,
                              void* d_out, int out_size, void* d_ws, size_t ws_size,
                              hipStream_t stream)
{
    const float* query       = (const float*)d_in[0];
    const unsigned char* kpm = (const unsigned char*)d_in[3];
    const float* w_in        = (const float*)d_in[4];
    const float* b_in        = (const float*)d_in[5];
    const float* w_out       = (const float*)d_in[6];
    const float* b_out       = (const float*)d_in[7];
    float* out = (float*)d_out;

    // workspace layout
    unsigned short* qb    = (unsigned short*)d_ws;          // query bf16     33.5 MB
    unsigned short* qphi  = qb    + NQ;                     // phi(q)         33.5 MB
    unsigned short* kpb   = qphi  + NQ;                     // phi(k)*mask    33.5 MB
    unsigned short* vmb   = kpb   + NQ;                     // v*mask         33.5 MB
    unsigned short* attnb = vmb   + NQ;                     // attn           33.5 MB
    unsigned short* wib   = attnb + NQ;                     // w_in bf16       1.6 MB
    unsigned short* wob   = wib   + 1536 * 512;             // w_out bf16      0.5 MB
    float* fmask   = (float*)(wob + 512 * 512);             // 128 KB
    float* part_kv = fmask + NROW;                          // 8.4 MB
    float* part_ks = part_kv + (size_t)512 * 4096;
    float* kv      = part_ks + 512 * 64;
    float* ksum    = kv + 32 * 4096;
    int*   flag    = (int*)(ksum + 32 * 64);

    hipLaunchKernelGGL(detect_mask, dim3(1), dim3(256), 0, stream, kpm, flag);
    hipLaunchKernelGGL(convert_all, dim3(16384), dim3(256), 0, stream,
                       query, qb, w_in, wib, w_out, wob, kpm, flag, fmask);

    // in-proj: M=32768, N=1536, K=512; epilogue -> qphi/kpb/vmb (bf16)
    hipLaunchKernelGGL(gemm_mfma, dim3(1536 / 128, NROW / 128), dim3(256), 0, stream,
                       qb, D_, wib, D_, b_in, D_, 0, fmask,
                       qphi, kpb, vmb, (float*)nullptr);

    hipLaunchKernelGGL(kv_reduce, dim3(32, 16), dim3(256), 0, stream, kpb, vmb, part_kv, part_ks);
    hipLaunchKernelGGL(kv_reduce2, dim3((32 * 4096) / 256), dim3(256), 0, stream,
                       part_kv, part_ks, kv, ksum);
    hipLaunchKernelGGL(apply_attn, dim3(32, S_ / 64), dim3(256), 0, stream, qphi, kv, ksum, attnb);

    // out-proj: M=32768, N=512, K=512 -> fp32 d_out
    hipLaunchKernelGGL(gemm_mfma, dim3(512 / 128, NROW / 128), dim3(256), 0, stream,
                       attnb, D_, wob, D_, b_out, D_, 1, (const float*)nullptr,
                       (unsigned short*)nullptr, (unsigned short*)nullptr,
                       (unsigned short*)nullptr, out);
}